// Round 1
// baseline (1826.394 us; speedup 1.0000x reference)
//
#include <hip/hip_runtime.h>
#include <cstdint>
#include <cstddef>

// ---------------- problem constants ----------------
#define VOCAB  50257
#define VPAD   50304          // 393 * 128, zero-padded W rows
#define DIMK   768
#define MROWS  4096           // B*S = 2*2048
#define NBLK   393            // VPAD / 128
#define MBLK   32             // MROWS / 128
#define NWG    (NBLK * MBLK)  // 12576, % 8 == 0 -> simple XCD swizzle is bijective
#define KSTEPS (DIMK / 32)    // 24
#define LSCALE 20.0f          // 1/eps

typedef __bf16 bf16x8 __attribute__((ext_vector_type(8)));
typedef float  floatx4 __attribute__((ext_vector_type(4)));

typedef const void __attribute__((address_space(1)))* gptr1_t;
typedef void __attribute__((address_space(3)))* lptr3_t;

__device__ __forceinline__ void async_copy16(const void* g, void* l) {
  // 16B/lane direct global->LDS; LDS dest is wave-uniform base + lane*16
  __builtin_amdgcn_global_load_lds((gptr1_t)g, (lptr3_t)l, 16, 0, 0);
}

__device__ __forceinline__ unsigned short f2bf(float f) {
  union { float f; unsigned u; } x; x.f = f;
  unsigned r = x.u + 0x7fffu + ((x.u >> 16) & 1u);   // RNE (finite inputs)
  return (unsigned short)(r >> 16);
}

// ---------------- stage 1: row L2-normalize, fp32 -> bf16 ----------------
// one block per row, 256 threads, D=768 -> 3 elems/thread.
// rows >= valid_rows are written as zeros (W padding).
__global__ void norm_rows_kernel(const float* __restrict__ in,
                                 unsigned short* __restrict__ outb,
                                 int valid_rows) {
  const int row = blockIdx.x;
  const int t = threadIdx.x;
  float v0 = 0.f, v1 = 0.f, v2 = 0.f;
  if (row < valid_rows) {
    const float* p = in + (size_t)row * DIMK;
    v0 = p[t]; v1 = p[t + 256]; v2 = p[t + 512];
  }
  float ss = v0 * v0 + v1 * v1 + v2 * v2;
#pragma unroll
  for (int off = 32; off > 0; off >>= 1) ss += __shfl_xor(ss, off);
  __shared__ float wss[4];
  if ((t & 63) == 0) wss[t >> 6] = ss;
  __syncthreads();
  const float tot = wss[0] + wss[1] + wss[2] + wss[3];
  const float sc = 1.0f / fmaxf(sqrtf(tot), 1e-12f);  // matches F.normalize
  unsigned short* q = outb + (size_t)row * DIMK;
  q[t]       = f2bf(v0 * sc);
  q[t + 256] = f2bf(v1 * sc);
  q[t + 512] = f2bf(v2 * sc);
}

// ---------------- stage 2: bf16 GEMM + exp-sum epilogue -------------------
// C[m,n] = sum_k A[m,k]*B[n,k]  (B stored row-major [N][K] == B^T GEMM)
// 128x128 tile, BK=32, 4 waves of 2x2 x (64x64 per wave), 16x16x32 MFMA.
// Changes vs prev round:
//  - double-buffered LDS, T3-min 2-phase: issue next tile's global_load_lds
//    BEFORE computing current tile; single __syncthreads per K-step (its
//    implicit vmcnt(0) drain lands after a full MFMA phase).
//  - XOR swizzle of the 16B k-chunk with (row>>1)&3: ds_read_b128 quarter-wave
//    goes from 8-way bank serialization to free 2-way. global_load_lds writes
//    LDS linearly, so the involution is applied to the GLOBAL source address
//    and to the LDS READ address (both-sides rule).
//  - nontemporal stores for `out` so the 862 MB write stream stops evicting
//    B (77 MB) from L3 -> FETCH_SIZE should collapse toward A+B footprint.
//  - uniform tail branch: only blockIdx with colBase+128 > VOCAB pays the
//    per-element mask.
//  - XCD-chunked bijective block swizzle (nwg % 8 == 0).
__global__ __launch_bounds__(256)
void gemm_kernel(const unsigned short* __restrict__ A,   // [MROWS][K] bf16
                 const unsigned short* __restrict__ Bw,  // [VPAD][K] bf16
                 float* __restrict__ out,                // [MROWS][VOCAB]
                 float* __restrict__ row_sums) {         // [MROWS]
  __shared__ __align__(16) unsigned short As[2][128 * 32];
  __shared__ __align__(16) unsigned short Bs[2][128 * 32];
  const int tid  = threadIdx.x;
  const int wave = tid >> 6;
  const int lane = tid & 63;
  const int lhi  = lane >> 4;   // quad 0..3
  const int llo  = lane & 15;
  const int wm   = wave >> 1;   // wave row 0..1
  const int wn   = wave & 1;    // wave col 0..1

  // XCD-aware chunked swizzle: dispatch round-robins XCDs on blockIdx.x%8;
  // give each XCD a contiguous 1/8 chunk of the (col-fastest) work space.
  const int orig = (int)blockIdx.x;
  const int swz  = (orig & 7) * (NWG / 8) + (orig >> 3);
  const int by   = swz / NBLK;
  const int bx   = swz - by * NBLK;
  const int rowBase = by * 128;
  const int colBase = bx * 128;

  floatx4 acc[4][4];
#pragma unroll
  for (int i = 0; i < 4; ++i)
#pragma unroll
    for (int j = 0; j < 4; ++j)
      acc[i][j] = (floatx4){0.f, 0.f, 0.f, 0.f};

  // staging: 512 x 16B chunks per tile; chunk c -> row c>>2, k-chunk c&3.
  // LDS slot (r, q) receives GLOBAL k-chunk q ^ ((r>>1)&3)  (XOR involution).
  const int c0 = (wave * 2 + 0) * 64 + lane;
  const int c1 = (wave * 2 + 1) * 64 + lane;
  const int r0 = c0 >> 2, r1 = c1 >> 2;
  const int q0 = (c0 & 3) ^ ((r0 >> 1) & 3);
  const int q1 = (c1 & 3) ^ ((r1 >> 1) & 3);
  const unsigned short* Ag0 = A  + (size_t)(rowBase + r0) * DIMK + q0 * 8;
  const unsigned short* Ag1 = A  + (size_t)(rowBase + r1) * DIMK + q1 * 8;
  const unsigned short* Bg0 = Bw + (size_t)(colBase + r0) * DIMK + q0 * 8;
  const unsigned short* Bg1 = Bw + (size_t)(colBase + r1) * DIMK + q1 * 8;
  const int l0 = (wave * 2 + 0) * 512;   // shorts; == chunk-linear order
  const int l1 = (wave * 2 + 1) * 512;

  // prologue: stage tile 0 into buffer 0
  async_copy16(Ag0, &As[0][l0]);
  async_copy16(Ag1, &As[0][l1]);
  async_copy16(Bg0, &Bs[0][l0]);
  async_copy16(Bg1, &Bs[0][l1]);
  __syncthreads();   // compiler drains vmcnt(0) here -> tile 0 resident

  // read-side swizzled k-chunk: row = ..+llo  ->  (row>>1)&3 == (llo>>1)&3
  const int kcS = (lhi ^ ((llo >> 1) & 3)) * 8;

  int cur = 0;
  for (int kt = 0; kt < KSTEPS; ++kt) {
    if (kt + 1 < KSTEPS) {               // issue next tile under this compute
      const int kn = (kt + 1) * 32;
      const int nb = cur ^ 1;
      async_copy16(Ag0 + kn, &As[nb][l0]);
      async_copy16(Ag1 + kn, &As[nb][l1]);
      async_copy16(Bg0 + kn, &Bs[nb][l0]);
      async_copy16(Bg1 + kn, &Bs[nb][l1]);
    }
    bf16x8 af[4], bfr[4];
#pragma unroll
    for (int fr = 0; fr < 4; ++fr)
      af[fr] = *(const bf16x8*)&As[cur][(wm * 64 + fr * 16 + llo) * 32 + kcS];
#pragma unroll
    for (int fc = 0; fc < 4; ++fc)
      bfr[fc] = *(const bf16x8*)&Bs[cur][(wn * 64 + fc * 16 + llo) * 32 + kcS];
#pragma unroll
    for (int fr = 0; fr < 4; ++fr)
#pragma unroll
      for (int fc = 0; fc < 4; ++fc)
        acc[fr][fc] = __builtin_amdgcn_mfma_f32_16x16x32_bf16(
            af[fr], bfr[fc], acc[fr][fc], 0, 0, 0);
    __syncthreads();   // drains next-tile staging + guards buffer reuse
    cur ^= 1;
  }

  // epilogue: l = 20*cos; nt-store; accumulate sum(exp(l-20)) per row.
  // C/D layout: col = lane&15, row = quad*4 + reg  (verified m89/m91)
  const bool tail = (colBase + 128 > VOCAB);   // true only for bx == NBLK-1
  float myrowsum = 0.f;
  int   myrow = rowBase + wm * 64;
#pragma unroll
  for (int fr = 0; fr < 4; ++fr) {
#pragma unroll
    for (int r = 0; r < 4; ++r) {
      const int grow = rowBase + wm * 64 + fr * 16 + lhi * 4 + r;
      float* orow = out + (size_t)grow * VOCAB + colBase + wn * 64;
      float s = 0.f;
      if (!tail) {
#pragma unroll
        for (int fc = 0; fc < 4; ++fc) {
          const float l = acc[fr][fc][r] * LSCALE;
          __builtin_nontemporal_store(l, &orow[fc * 16 + llo]);
          s += __expf(l - LSCALE);   // fixed max = 20 (|l| <= 20)
        }
      } else {
#pragma unroll
        for (int fc = 0; fc < 4; ++fc) {
          const int gcol = colBase + wn * 64 + fc * 16 + llo;
          if (gcol < VOCAB) {
            const float l = acc[fr][fc][r] * LSCALE;
            __builtin_nontemporal_store(l, &orow[fc * 16 + llo]);
            s += __expf(l - LSCALE);
          }
        }
      }
      // reduce across the 16 lanes sharing this row (xor 1,2,4,8)
      s += __shfl_xor(s, 1);
      s += __shfl_xor(s, 2);
      s += __shfl_xor(s, 4);
      s += __shfl_xor(s, 8);
      if (llo == fr * 4 + r) { myrowsum = s; myrow = grow; }
    }
  }
  atomicAdd(&row_sums[myrow], myrowsum);  // one atomic per lane, 64/wave
}

// ---------------- stage 3: lse = 20 + log(sum) ----------------
__global__ void lse_fin_kernel(const float* __restrict__ sums,
                               float* __restrict__ lse) {
  const int i = blockIdx.x * 256 + threadIdx.x;
  if (i < MROWS) lse[i] = LSCALE + logf(sums[i]);
}

// ---------------- stage 4: out = l - lse[row] + bias[col] ----------------
// grid-stride streaming RMW; nontemporal (no reuse); one div per float4.
#define TOT4 51463168u   // (4096*50257)/4, exact
__global__ __launch_bounds__(256)
void apply_kernel(float* __restrict__ out,
                  const float* __restrict__ lse,
                  const float* __restrict__ bias) {
  const unsigned stride = gridDim.x * 256u;
  floatx4* o4 = reinterpret_cast<floatx4*>(out);
  for (unsigned i = blockIdx.x * 256u + threadIdx.x; i < TOT4; i += stride) {
    floatx4 v = __builtin_nontemporal_load(o4 + i);
    const unsigned b0 = i * 4u;
    unsigned row = b0 / (unsigned)VOCAB;
    unsigned col = b0 - row * (unsigned)VOCAB;
    float lr = lse[row];
#pragma unroll
    for (int j = 0; j < 4; ++j) {
      if (col == (unsigned)VOCAB) { col = 0u; ++row; lr = lse[row]; }
      v[j] = v[j] - lr + bias[col];
      ++col;
    }
    __builtin_nontemporal_store(v, o4 + i);
  }
}

// ---------------- launch ----------------
extern "C" void kernel_launch(void* const* d_in, const int* in_sizes, int n_in,
                              void* d_out, int out_size, void* d_ws, size_t ws_size,
                              hipStream_t stream) {
  const float* x    = (const float*)d_in[0];   // [2,2048,768]
  const float* w    = (const float*)d_in[1];   // [50257,768]
  const float* bias = (const float*)d_in[2];   // [50257]
  float* out = (float*)d_out;                  // [4096,50257]

  // workspace layout (ws re-poisoned each call -> re-init everything we need)
  unsigned short* xn = (unsigned short*)d_ws;              // 4096*768 bf16
  unsigned short* wn = xn + (size_t)MROWS * DIMK;          // 50304*768 bf16
  float* sums = (float*)(wn + (size_t)VPAD * DIMK);        // 4096 f32
  float* lse  = sums + MROWS;                              // 4096 f32

  hipMemsetAsync(sums, 0, MROWS * sizeof(float), stream);
  norm_rows_kernel<<<MROWS, 256, 0, stream>>>(x, xn, MROWS);
  norm_rows_kernel<<<VPAD, 256, 0, stream>>>(w, wn, VOCAB);
  gemm_kernel<<<NWG, 256, 0, stream>>>(xn, wn, out, sums);
  lse_fin_kernel<<<(MROWS + 255) / 256, 256, 0, stream>>>(sums, lse);
  apply_kernel<<<4096, 256, 0, stream>>>(out, lse, bias);
}